// Round 11
// baseline (83.903 us; speedup 1.0000x reference)
//
#include <hip/hip_runtime.h>
#include <hip/hip_bf16.h>

// ListMLE: mean(cumlogsumexp(gather(outputs, labels), axis=1) - outputs)
// B=8192 rows, N=4096 cols. outputs fp32, labels int32 (per-row permutation).
// R11: R6's exact structure (fp32 LDS double-buffer + register prefetch
//      pipeline, lgkm-only mid barrier) at BLOCK=512 / PER_THREAD=8.
//      LDS 2x16KB caps blocks at 4/CU either way; 512-thread blocks make that
//      4 x 8 = 32 waves/CU (R6: 16). Prefetch live set halves (16 VGPR), so
//      (512,4) [the never-spilled budget-128 bound] should land ~50 VGPR,
//      <=64 -> HW allows 8 waves/EU. ROWS=8, grid 1024 = exact 4 blocks/CU.

#define N_COLS 4096
#define BLOCK 512
#define PER_THREAD (N_COLS / BLOCK)  // 8
#define NWAVES (BLOCK / 64)          // 8
#define ROWS 8
#define LOG2E 1.4426950408889634f
#define LN2   0.6931471805599453f

__global__ __launch_bounds__(BLOCK, 4) void listmle_rows_kernel(
    const float* __restrict__ outputs,
    const int*   __restrict__ labels,
    double*      __restrict__ partials)
{
    __shared__ float buf[2][N_COLS];        // 2 x 16 KB double buffer
    __shared__ float wave_t[NWAVES];
    __shared__ float wsum[NWAVES];

    const int tid  = threadIdx.x;
    const int lane = tid & 63;
    const int wid  = tid >> 6;
    const size_t row0  = (size_t)blockIdx.x * ROWS;
    const int    start = tid * PER_THREAD;

    // ---- prologue: row 0 labels+outputs to regs, stage buf[0] ----
    int4   lf0, lf1;
    float4 of0, of1;
    {
        const int4* lrow = (const int4*)(labels + row0 * N_COLS + start);
        lf0 = lrow[0]; lf1 = lrow[1];
        const float4* orow = (const float4*)(outputs + row0 * N_COLS);
        of0 = orow[tid]; of1 = orow[tid + 512];
    }
    {
        float4* b0 = (float4*)buf[0];
        b0[tid] = of0; b0[tid + 512] = of1;
    }
    __syncthreads();

    float total_contrib = 0.0f;
    int cur = 0;

    for (int k = 0; k < ROWS; ++k) {
        // current row's labels -> static-indexed array
        int labs[PER_THREAD] = { lf0.x, lf0.y, lf0.z, lf0.w,
                                 lf1.x, lf1.y, lf1.z, lf1.w };

        // issue next-row loads: labels first, outputs second
        if (k + 1 < ROWS) {
            const int4* lrow = (const int4*)(labels + (row0 + k + 1) * N_COLS + start);
            lf0 = lrow[0]; lf1 = lrow[1];
            const float4* orow = (const float4*)(outputs + (row0 + k + 1) * N_COLS);
            of0 = orow[tid]; of1 = orow[tid + 512];
        }

        // gather + exp2 + thread-local prefix sums (from current buffer)
        const float* cb = buf[cur];
        float p[PER_THREAD];
        float x_sum = 0.0f, run = 0.0f;
        #pragma unroll
        for (int j = 0; j < PER_THREAD; ++j) {
            float xv = cb[labs[j]];
            x_sum += xv;
            run += exp2f(xv * LOG2E);
            p[j] = run;
        }

        // wave-level inclusive scan of thread totals
        float inc = run;
        #pragma unroll
        for (int d = 1; d < 64; d <<= 1) {
            float v = __shfl_up(inc, d, 64);
            if (lane >= d) inc += v;
        }
        float excl = inc - run;
        if (lane == 63) wave_t[wid] = inc;

        // lgkm-only barrier: next-row global loads stay in flight
        asm volatile("s_waitcnt lgkmcnt(0)" ::: "memory");
        __builtin_amdgcn_s_barrier();

        // exclusive wave prefix via broadcast reads
        float E = excl;
        #pragma unroll
        for (int w = 0; w < NWAVES - 1; ++w)
            if (w < wid) E += wave_t[w];

        // scores: 8 independent log2s
        float acc = 0.0f;
        #pragma unroll
        for (int j = 0; j < PER_THREAD; ++j)
            acc += __log2f(E + p[j]);
        total_contrib += LN2 * acc - x_sum;

        // stage next row into the other buffer (vmcnt wait lands here)
        if (k + 1 < ROWS) {
            float4* nb = (float4*)buf[cur ^ 1];
            nb[tid] = of0; nb[tid + 512] = of1;
        }
        __syncthreads();   // row boundary
        cur ^= 1;
    }

    // ---- block reduce total contribution, plain store per block ----
    #pragma unroll
    for (int d = 32; d > 0; d >>= 1)
        total_contrib += __shfl_down(total_contrib, d, 64);
    if (lane == 0) wsum[wid] = total_contrib;
    __syncthreads();
    if (tid == 0) {
        float tot = 0.0f;
        #pragma unroll
        for (int w = 0; w < NWAVES; ++w) tot += wsum[w];
        partials[blockIdx.x] = (double)tot;
    }
}

// One block: reduce partial doubles, write mean as float.
__global__ __launch_bounds__(256) void listmle_reduce_kernel(
    const double* __restrict__ partials,
    float* __restrict__ out,
    int nblocks,
    double inv_count)
{
    __shared__ double wtot[4];
    const int tid  = threadIdx.x;
    const int lane = tid & 63;
    const int wid  = tid >> 6;

    double sum = 0.0;
    for (int i = tid; i < nblocks; i += 256)
        sum += partials[i];

    #pragma unroll
    for (int d = 32; d > 0; d >>= 1)
        sum += __shfl_down(sum, d, 64);
    if (lane == 0) wtot[wid] = sum;
    __syncthreads();
    if (tid == 0) {
        double tot = 0.0;
        #pragma unroll
        for (int w = 0; w < 4; ++w) tot += wtot[w];
        out[0] = (float)(tot * inv_count);
    }
}

extern "C" void kernel_launch(void* const* d_in, const int* in_sizes, int n_in,
                              void* d_out, int out_size, void* d_ws, size_t ws_size,
                              hipStream_t stream)
{
    const float* outputs = (const float*)d_in[0];
    const int*   labels  = (const int*)d_in[1];
    float*  out = (float*)d_out;
    double* partials = (double*)d_ws;

    const int total = in_sizes[0];          // B * N
    const int B = total / N_COLS;           // 8192
    const int nblocks = B / ROWS;           // 1024

    listmle_rows_kernel<<<nblocks, BLOCK, 0, stream>>>(outputs, labels, partials);
    listmle_reduce_kernel<<<1, 256, 0, stream>>>(partials, out, nblocks,
                                                 1.0 / (double)total);
}

// Round 12
// 50.869 us; speedup vs baseline: 1.6494x; 1.6494x over previous
//
#include <hip/hip_runtime.h>
#include <hip/hip_bf16.h>

// ListMLE: mean(cumlogsumexp(gather(outputs, labels), axis=1) - outputs)
// B=8192 rows, N=4096 cols. outputs fp32, labels int32 (per-row permutation).
// R12: R11 structure (fp32 LDS double-buffer + reg prefetch pipeline,
//      512 threads / 8 per thread) with launch_bounds(512,2).
//      Empirical allocator model (R6..R11): hipcc treats the 2nd arg as
//      min BLOCKS/CU -> VGPR cap = 512/(blocks*waves_per_block/4).
//      (512,4) capped at 64 -> spilled (R11: WRITE 70MB). (512,2) -> cap 128,
//      same budget as R6's clean 52-VGPR compile, live set here is smaller.
//      Actual occupancy follows actual allocation: <=64 VGPR -> 8 waves/EU,
//      LDS 33KB -> 4 blocks/CU -> 32 waves/CU with the pipeline intact.

#define N_COLS 4096
#define BLOCK 512
#define PER_THREAD (N_COLS / BLOCK)  // 8
#define NWAVES (BLOCK / 64)          // 8
#define ROWS 8
#define LOG2E 1.4426950408889634f
#define LN2   0.6931471805599453f

__global__ __launch_bounds__(BLOCK, 2) void listmle_rows_kernel(
    const float* __restrict__ outputs,
    const int*   __restrict__ labels,
    double*      __restrict__ partials)
{
    __shared__ float buf[2][N_COLS];        // 2 x 16 KB double buffer
    __shared__ float wave_t[NWAVES];
    __shared__ float wsum[NWAVES];

    const int tid  = threadIdx.x;
    const int lane = tid & 63;
    const int wid  = tid >> 6;
    const size_t row0  = (size_t)blockIdx.x * ROWS;
    const int    start = tid * PER_THREAD;

    // ---- prologue: row 0 labels+outputs to regs, stage buf[0] ----
    int4   lf0, lf1;
    float4 of0, of1;
    {
        const int4* lrow = (const int4*)(labels + row0 * N_COLS + start);
        lf0 = lrow[0]; lf1 = lrow[1];
        const float4* orow = (const float4*)(outputs + row0 * N_COLS);
        of0 = orow[tid]; of1 = orow[tid + 512];
    }
    {
        float4* b0 = (float4*)buf[0];
        b0[tid] = of0; b0[tid + 512] = of1;
    }
    __syncthreads();

    float total_contrib = 0.0f;
    int cur = 0;

    for (int k = 0; k < ROWS; ++k) {
        // current row's labels -> static-indexed array
        int labs[PER_THREAD] = { lf0.x, lf0.y, lf0.z, lf0.w,
                                 lf1.x, lf1.y, lf1.z, lf1.w };

        // issue next-row loads: labels first, outputs second
        if (k + 1 < ROWS) {
            const int4* lrow = (const int4*)(labels + (row0 + k + 1) * N_COLS + start);
            lf0 = lrow[0]; lf1 = lrow[1];
            const float4* orow = (const float4*)(outputs + (row0 + k + 1) * N_COLS);
            of0 = orow[tid]; of1 = orow[tid + 512];
        }

        // gather + exp2 + thread-local prefix sums (from current buffer)
        const float* cb = buf[cur];
        float p[PER_THREAD];
        float x_sum = 0.0f, run = 0.0f;
        #pragma unroll
        for (int j = 0; j < PER_THREAD; ++j) {
            float xv = cb[labs[j]];
            x_sum += xv;
            run += exp2f(xv * LOG2E);
            p[j] = run;
        }

        // wave-level inclusive scan of thread totals
        float inc = run;
        #pragma unroll
        for (int d = 1; d < 64; d <<= 1) {
            float v = __shfl_up(inc, d, 64);
            if (lane >= d) inc += v;
        }
        float excl = inc - run;
        if (lane == 63) wave_t[wid] = inc;

        // lgkm-only barrier: next-row global loads stay in flight
        asm volatile("s_waitcnt lgkmcnt(0)" ::: "memory");
        __builtin_amdgcn_s_barrier();

        // exclusive wave prefix via broadcast reads
        float E = excl;
        #pragma unroll
        for (int w = 0; w < NWAVES - 1; ++w)
            if (w < wid) E += wave_t[w];

        // scores: 8 independent log2s
        float acc = 0.0f;
        #pragma unroll
        for (int j = 0; j < PER_THREAD; ++j)
            acc += __log2f(E + p[j]);
        total_contrib += LN2 * acc - x_sum;

        // stage next row into the other buffer (vmcnt wait lands here)
        if (k + 1 < ROWS) {
            float4* nb = (float4*)buf[cur ^ 1];
            nb[tid] = of0; nb[tid + 512] = of1;
        }
        __syncthreads();   // row boundary
        cur ^= 1;
    }

    // ---- block reduce total contribution, plain store per block ----
    #pragma unroll
    for (int d = 32; d > 0; d >>= 1)
        total_contrib += __shfl_down(total_contrib, d, 64);
    if (lane == 0) wsum[wid] = total_contrib;
    __syncthreads();
    if (tid == 0) {
        float tot = 0.0f;
        #pragma unroll
        for (int w = 0; w < NWAVES; ++w) tot += wsum[w];
        partials[blockIdx.x] = (double)tot;
    }
}

// One block: reduce partial doubles, write mean as float.
__global__ __launch_bounds__(256) void listmle_reduce_kernel(
    const double* __restrict__ partials,
    float* __restrict__ out,
    int nblocks,
    double inv_count)
{
    __shared__ double wtot[4];
    const int tid  = threadIdx.x;
    const int lane = tid & 63;
    const int wid  = tid >> 6;

    double sum = 0.0;
    for (int i = tid; i < nblocks; i += 256)
        sum += partials[i];

    #pragma unroll
    for (int d = 32; d > 0; d >>= 1)
        sum += __shfl_down(sum, d, 64);
    if (lane == 0) wtot[wid] = sum;
    __syncthreads();
    if (tid == 0) {
        double tot = 0.0;
        #pragma unroll
        for (int w = 0; w < 4; ++w) tot += wtot[w];
        out[0] = (float)(tot * inv_count);
    }
}

extern "C" void kernel_launch(void* const* d_in, const int* in_sizes, int n_in,
                              void* d_out, int out_size, void* d_ws, size_t ws_size,
                              hipStream_t stream)
{
    const float* outputs = (const float*)d_in[0];
    const int*   labels  = (const int*)d_in[1];
    float*  out = (float*)d_out;
    double* partials = (double*)d_ws;

    const int total = in_sizes[0];          // B * N
    const int B = total / N_COLS;           // 8192
    const int nblocks = B / ROWS;           // 1024

    listmle_rows_kernel<<<nblocks, BLOCK, 0, stream>>>(outputs, labels, partials);
    listmle_reduce_kernel<<<1, 256, 0, stream>>>(partials, out, nblocks,
                                                 1.0 / (double)total);
}

// Round 13
// 47.616 us; speedup vs baseline: 1.7621x; 1.0683x over previous
//
#include <hip/hip_runtime.h>
#include <hip/hip_bf16.h>

// ListMLE: mean(cumlogsumexp(gather(outputs, labels), axis=1) - outputs)
// B=8192 rows, N=4096 cols. outputs fp32, labels int32 (per-row permutation).
// R13: R12 shell (512 thr, fp32 LDS dbuf, reg prefetch, lgkm-only barrier,
//      launch_bounds(512,2) = budget 128, verified spill-free) with the
//      per-row critical path shortened:
//      - LDS stores e = 2^(x*log2e), computed at STAGING from coalesced regs
//        (trans latency hides under in-flight loads; gather chain = pure adds)
//      - x_sum from coalesced regs at staging (carried one iter, like R8)
//      - product-batched logs: 8 log2s -> 2 log2s + 6 muls
//        (groups of 4; products <= ~1e16, fp32-safe, rel err ~2e-7)

#define N_COLS 4096
#define BLOCK 512
#define PER_THREAD (N_COLS / BLOCK)  // 8
#define NWAVES (BLOCK / 64)          // 8
#define ROWS 8
#define LOG2E 1.4426950408889634f
#define LN2   0.6931471805599453f

__global__ __launch_bounds__(BLOCK, 2) void listmle_rows_kernel(
    const float* __restrict__ outputs,
    const int*   __restrict__ labels,
    double*      __restrict__ partials)
{
    __shared__ float ebuf[2][N_COLS];       // 2 x 16 KB e-value double buffer
    __shared__ float wave_t[NWAVES];
    __shared__ float wsum[NWAVES];

    const int tid  = threadIdx.x;
    const int lane = tid & 63;
    const int wid  = tid >> 6;
    const size_t row0  = (size_t)blockIdx.x * ROWS;
    const int    start = tid * PER_THREAD;

    // ---- prologue: row 0 -> regs; xsum0; convert; stage buf[0] ----
    int4   lf0, lf1;
    float4 of0, of1;
    {
        const int4* lrow = (const int4*)(labels + row0 * N_COLS + start);
        lf0 = lrow[0]; lf1 = lrow[1];
        const float4* orow = (const float4*)(outputs + row0 * N_COLS);
        of0 = orow[tid]; of1 = orow[tid + 512];
    }
    float xsum_cur = (of0.x + of0.y + of0.z + of0.w)
                   + (of1.x + of1.y + of1.z + of1.w);
    {
        float4 e0, e1;
        e0.x = exp2f(of0.x * LOG2E); e0.y = exp2f(of0.y * LOG2E);
        e0.z = exp2f(of0.z * LOG2E); e0.w = exp2f(of0.w * LOG2E);
        e1.x = exp2f(of1.x * LOG2E); e1.y = exp2f(of1.y * LOG2E);
        e1.z = exp2f(of1.z * LOG2E); e1.w = exp2f(of1.w * LOG2E);
        float4* b0 = (float4*)ebuf[0];
        b0[tid] = e0; b0[tid + 512] = e1;
    }
    __syncthreads();

    float total_contrib = 0.0f;
    int cur = 0;

    for (int k = 0; k < ROWS; ++k) {
        // current row's labels -> static-indexed array
        int labs[PER_THREAD] = { lf0.x, lf0.y, lf0.z, lf0.w,
                                 lf1.x, lf1.y, lf1.z, lf1.w };

        // issue next-row loads: labels first, outputs second
        if (k + 1 < ROWS) {
            const int4* lrow = (const int4*)(labels + (row0 + k + 1) * N_COLS + start);
            lf0 = lrow[0]; lf1 = lrow[1];
            const float4* orow = (const float4*)(outputs + (row0 + k + 1) * N_COLS);
            of0 = orow[tid]; of1 = orow[tid + 512];
        }

        // gather e-values in label order: pure add chain fed by LDS reads
        const float* cb = ebuf[cur];
        float p[PER_THREAD];
        float run = 0.0f;
        #pragma unroll
        for (int j = 0; j < PER_THREAD; ++j) {
            run += cb[labs[j]];
            p[j] = run;
        }

        // wave-level inclusive scan of thread totals
        float inc = run;
        #pragma unroll
        for (int d = 1; d < 64; d <<= 1) {
            float v = __shfl_up(inc, d, 64);
            if (lane >= d) inc += v;
        }
        float excl = inc - run;
        if (lane == 63) wave_t[wid] = inc;

        // lgkm-only barrier: next-row global loads stay in flight
        asm volatile("s_waitcnt lgkmcnt(0)" ::: "memory");
        __builtin_amdgcn_s_barrier();

        // exclusive wave prefix via broadcast reads
        float E = excl;
        #pragma unroll
        for (int w = 0; w < NWAVES - 1; ++w)
            if (w < wid) E += wave_t[w];

        // stage next row: xsum + exp2 from coalesced regs (vmcnt wait lands
        // here, hidden by the logs below), ds_write to other buffer
        float xsum_next = 0.0f;
        if (k + 1 < ROWS) {
            xsum_next = (of0.x + of0.y + of0.z + of0.w)
                      + (of1.x + of1.y + of1.z + of1.w);
            float4 e0, e1;
            e0.x = exp2f(of0.x * LOG2E); e0.y = exp2f(of0.y * LOG2E);
            e0.z = exp2f(of0.z * LOG2E); e0.w = exp2f(of0.w * LOG2E);
            e1.x = exp2f(of1.x * LOG2E); e1.y = exp2f(of1.y * LOG2E);
            e1.z = exp2f(of1.z * LOG2E); e1.w = exp2f(of1.w * LOG2E);
            float4* nb = (float4*)ebuf[cur ^ 1];
            nb[tid] = e0; nb[tid + 512] = e1;
        }

        // scores: product-batched logs (2 log2s instead of 8)
        float q0 = (E + p[0]) * (E + p[1]);
        q0 *= (E + p[2]) * (E + p[3]);
        float q1 = (E + p[4]) * (E + p[5]);
        q1 *= (E + p[6]) * (E + p[7]);
        float acc = __log2f(q0) + __log2f(q1);
        total_contrib += LN2 * acc - xsum_cur;
        xsum_cur = xsum_next;

        __syncthreads();   // row boundary: other buffer fully staged
        cur ^= 1;
    }

    // ---- block reduce total contribution, plain store per block ----
    #pragma unroll
    for (int d = 32; d > 0; d >>= 1)
        total_contrib += __shfl_down(total_contrib, d, 64);
    if (lane == 0) wsum[wid] = total_contrib;
    __syncthreads();
    if (tid == 0) {
        float tot = 0.0f;
        #pragma unroll
        for (int w = 0; w < NWAVES; ++w) tot += wsum[w];
        partials[blockIdx.x] = (double)tot;
    }
}

// One block: reduce partial doubles, write mean as float.
__global__ __launch_bounds__(256) void listmle_reduce_kernel(
    const double* __restrict__ partials,
    float* __restrict__ out,
    int nblocks,
    double inv_count)
{
    __shared__ double wtot[4];
    const int tid  = threadIdx.x;
    const int lane = tid & 63;
    const int wid  = tid >> 6;

    double sum = 0.0;
    for (int i = tid; i < nblocks; i += 256)
        sum += partials[i];

    #pragma unroll
    for (int d = 32; d > 0; d >>= 1)
        sum += __shfl_down(sum, d, 64);
    if (lane == 0) wtot[wid] = sum;
    __syncthreads();
    if (tid == 0) {
        double tot = 0.0;
        #pragma unroll
        for (int w = 0; w < 4; ++w) tot += wtot[w];
        out[0] = (float)(tot * inv_count);
    }
}

extern "C" void kernel_launch(void* const* d_in, const int* in_sizes, int n_in,
                              void* d_out, int out_size, void* d_ws, size_t ws_size,
                              hipStream_t stream)
{
    const float* outputs = (const float*)d_in[0];
    const int*   labels  = (const int*)d_in[1];
    float*  out = (float*)d_out;
    double* partials = (double*)d_ws;

    const int total = in_sizes[0];          // B * N
    const int B = total / N_COLS;           // 8192
    const int nblocks = B / ROWS;           // 1024

    listmle_rows_kernel<<<nblocks, BLOCK, 0, stream>>>(outputs, labels, partials);
    listmle_reduce_kernel<<<1, 256, 0, stream>>>(partials, out, nblocks,
                                                 1.0 / (double)total);
}